// Round 5
// baseline (516.025 us; speedup 1.0000x reference)
//
#include <hip/hip_runtime.h>
#include <cstdint>

#define SEQn   2048
#define NHn    16
#define HDn    128
#define DMn    2048   // NH*HD
#define HIDn   2048
#define BATCHn 2
#define WINn   256
#define MROWS  (BATCHn*SEQn)  // 4096

typedef short s16x8 __attribute__((ext_vector_type(8)));  // 8 bf16 (4 VGPRs)
typedef float f32x4 __attribute__((ext_vector_type(4)));  // MFMA accumulator

typedef __attribute__((address_space(3))) uint lds_u32_t;
typedef const __attribute__((address_space(1))) uint glb_u32_t;
#define GLOAD_LDS16(g, s) \
    __builtin_amdgcn_global_load_lds((glb_u32_t*)(g), (lds_u32_t*)(s), 16, 0, 0)

__device__ __forceinline__ float bf2f(ushort x) {
    union { uint u; float f; } v; v.u = ((uint)x) << 16; return v.f;
}
__device__ __forceinline__ ushort f2bf(float f) {
    union { float f; uint u; } v; v.f = f;
    uint u = v.u;
    return (ushort)((u + 0x7FFFu + ((u >> 16) & 1u)) >> 16);  // RNE
}

// ---------------- x fp32 -> bf16 convert (coalesced, float4 in / ushort4 out)
__global__ __launch_bounds__(256)
void cvt_kernel(const float* __restrict__ src, ushort* __restrict__ dst)
{
    const int i = (blockIdx.x * 256 + threadIdx.x) * 4;
    const float4 v = *reinterpret_cast<const float4*>(src + i);
    ushort4 o;
    o.x = f2bf(v.x); o.y = f2bf(v.y); o.z = f2bf(v.z); o.w = f2bf(v.w);
    *reinterpret_cast<ushort4*>(dst + i) = o;
}

// ------- transpose+convert 2048x2048: W[k][n] fp32 -> WT[n][k] bf16 ----------
__global__ __launch_bounds__(256)
void transpose_cvt_kernel(const float* __restrict__ src, ushort* __restrict__ dst)
{
    __shared__ ushort t[32][33];
    const int tx = threadIdx.x, ty = threadIdx.y;
    const int n  = blockIdx.x * 32 + tx;
    const int k0 = blockIdx.y * 32;
    #pragma unroll
    for (int r = ty; r < 32; r += 8)
        t[r][tx] = f2bf(src[(size_t)(k0 + r) * 2048 + n]);
    __syncthreads();
    const int k  = k0 + tx;
    const int nb = blockIdx.x * 32;
    #pragma unroll
    for (int r = ty; r < 32; r += 8)
        dst[(size_t)(nb + r) * 2048 + k] = t[tx][r];
}

// ---------------- GEMM: C(MxN) = A(MxK) * BT(NxK)^T + bias ------------------
// m97 structure: unpadded LDS (stride 64 ushorts), global_load_lds width=16
// staging (wave-uniform base + lane*16 — layout verified). A, BT bf16.
// C_MODE: 0 = bf16 row-major, 1 = fp32 row-major, 2 = bf16 Vt [b][h][d][s].
// 128x128 tile, BK=64, 4 waves (2x2), wave tile 64x64 = 4x4 MFMA 16x16x32.
// C/D: col=lane&15, row=(lane>>4)*4+reg  (m89-verified mapping).
template<int C_MODE>
__global__ __launch_bounds__(256)
void gemm_bt_kernel(const ushort* __restrict__ A, const ushort* __restrict__ BT,
                    const float* __restrict__ bias, void* __restrict__ Craw,
                    int M, int N, int K)
{
    __shared__ __align__(16) ushort As[128 * 64];
    __shared__ __align__(16) ushort Bs[128 * 64];
    const int tid = threadIdx.x;
    const int m0 = blockIdx.y * 128;
    const int n0 = blockIdx.x * 128;
    const int w  = tid >> 6;
    const int l  = tid & 63;
    const int wy = w >> 1, wx = w & 1;
    const int q  = l >> 4, lm = l & 15;
    const int srow = tid >> 3;          // 0..31
    const int scol = (tid & 7) << 3;    // ushort col 0..56

    f32x4 acc[4][4];
    #pragma unroll
    for (int i = 0; i < 4; ++i)
        #pragma unroll
        for (int j = 0; j < 4; ++j) acc[i][j] = (f32x4)0.0f;

    for (int kt = 0; kt < K; kt += 64) {
        #pragma unroll
        for (int it = 0; it < 4; ++it) {
            const int r = it * 32 + srow;
            GLOAD_LDS16(A  + (size_t)(m0 + r) * K + kt + scol, &As[r * 64 + scol]);
            GLOAD_LDS16(BT + (size_t)(n0 + r) * K + kt + scol, &Bs[r * 64 + scol]);
        }
        __syncthreads();
        #pragma unroll
        for (int ks = 0; ks < 2; ++ks) {
            s16x8 af[4], bfv[4];
            #pragma unroll
            for (int im = 0; im < 4; ++im)
                af[im] = *reinterpret_cast<const s16x8*>(&As[(wy * 64 + im * 16 + lm) * 64 + ks * 32 + q * 8]);
            #pragma unroll
            for (int in = 0; in < 4; ++in)
                bfv[in] = *reinterpret_cast<const s16x8*>(&Bs[(wx * 64 + in * 16 + lm) * 64 + ks * 32 + q * 8]);
            #pragma unroll
            for (int im = 0; im < 4; ++im)
                #pragma unroll
                for (int in = 0; in < 4; ++in)
                    acc[im][in] = __builtin_amdgcn_mfma_f32_16x16x32_bf16(af[im], bfv[in], acc[im][in], 0, 0, 0);
        }
        __syncthreads();
    }
    #pragma unroll
    for (int in = 0; in < 4; ++in) {
        const int gcol = n0 + wx * 64 + in * 16 + lm;
        const float bv = bias[gcol];
        #pragma unroll
        for (int im = 0; im < 4; ++im) {
            const int grow0 = m0 + wy * 64 + im * 16 + q * 4;
            #pragma unroll
            for (int r = 0; r < 4; ++r) {
                const float val = acc[im][in][r] + bv;
                const int grow = grow0 + r;
                if (C_MODE == 0) {
                    ((ushort*)Craw)[(size_t)grow * N + gcol] = f2bf(val);
                } else if (C_MODE == 1) {
                    ((float*)Craw)[(size_t)grow * N + gcol] = val;
                } else {
                    // Vt[b][h][d][s]: b=grow>>11, s=grow&2047, h=gcol>>7, d=gcol&127
                    const int bb = grow >> 11, s = grow & (SEQn - 1);
                    const int hh = gcol >> 7,  d = gcol & (HDn - 1);
                    ((ushort*)Craw)[(((size_t)(bb * NHn + hh)) * HDn + d) * SEQn + s] = f2bf(val);
                }
            }
        }
    }
}

// ---------------- RoPE in-place on Q and K (bf16): layout (B,S,NH,128) -------
__global__ __launch_bounds__(256)
void rope_kernel(ushort* Qb, ushort* Kb)
{
    const int idx = blockIdx.x * 256 + threadIdx.x;   // (b,s,h,d2), d2 in [0,64)
    ushort* buf = (blockIdx.z == 0) ? Qb : Kb;
    const int d2 = idx & 63;
    const int s  = (idx >> 10) & (SEQn - 1);
    const size_t base = ((size_t)(idx >> 6)) * 128 + d2;
    const float invf = powf(10000.0f, -(float)d2 * (1.0f / 64.0f));
    const float ang = (float)s * invf;
    const float c = cosf(ang), sn = sinf(ang);
    const float t1 = bf2f(buf[base]);
    const float t2 = bf2f(buf[base + 64]);
    buf[base]      = f2bf(t1 * c - t2 * sn);
    buf[base + 64] = f2bf(t1 * sn + t2 * c);
}

// -------- MFMA flash attention: ONE WAVE per block, per (b, h, 16-q tile) ---
// Q: bf16 [b][s][h][d] (rope'd). K: bf16 [b][s][h][d] (rope'd).
// Vt: bf16 [b][h][d][s]. AO aliases Q in-place (1:1 wave<->rows mapping).
// All 8 K-frags + 8 V-frags prefetched at chunk start (V is independent of
// softmax -> pulls its latency off the serial chain).
__global__ __launch_bounds__(64)
void attn_mfma_kernel(const ushort* Q, const ushort* __restrict__ K,
                      const ushort* __restrict__ Vt, const float* __restrict__ kw,
                      ushort* AO)
{
    __shared__ ushort plds[16 * 40];   // P tile, stride 40 (2-way bank alias = free)
    const int l  = threadIdx.x;
    const int q  = l >> 4, lm = l & 15;
    const int gw = blockIdx.x;          // b(1) | h(4) | qt(7)
    const int qt = gw & 127;
    const int h  = (gw >> 7) & (NHn - 1);
    const int b  = gw >> 11;
    const int q0 = qt * 16;
    const float f = kw[h] * 0.08838834764831845f;   // kw * HD^-0.5

    s16x8 qf[4];
    const size_t qbase = ((size_t)(b * SEQn + q0 + lm)) * DMn + h * HDn;
    #pragma unroll
    for (int ks = 0; ks < 4; ++ks)
        qf[ks] = *reinterpret_cast<const s16x8*>(Q + qbase + ks * 32 + q * 8);

    f32x4 O[8];
    #pragma unroll
    for (int nt = 0; nt < 8; ++nt) O[nt] = (f32x4)0.0f;
    float m[4]    = {-1e30f, -1e30f, -1e30f, -1e30f};
    float lsum[4] = {0.f, 0.f, 0.f, 0.f};

    const int lo = q0 - WINn;
    const int c0 = lo > 0 ? (lo & ~31) : 0;
    const int nch = (q0 + 16 - c0 + 31) >> 5;

    const size_t kbh = ((size_t)(b * SEQn)) * DMn + h * HDn;
    const size_t vbh = ((size_t)(b * NHn + h)) * HDn * SEQn;

    for (int c = 0; c < nch; ++c) {
        const int kc = c0 + c * 32;
        // ---- prefetch: all K-frags and V-frags for this chunk ----
        s16x8 kf[8], vf[8];
        #pragma unroll
        for (int t = 0; t < 2; ++t) {
            const size_t krow = kbh + (size_t)(kc + t * 16 + lm) * DMn;
            #pragma unroll
            for (int ks = 0; ks < 4; ++ks)
                kf[t * 4 + ks] = *reinterpret_cast<const s16x8*>(K + krow + ks * 32 + q * 8);
        }
        #pragma unroll
        for (int nt = 0; nt < 8; ++nt)
            vf[nt] = *reinterpret_cast<const s16x8*>(
                Vt + vbh + (size_t)(nt * 16 + lm) * SEQn + kc + q * 8);
        // ---- QK^T: two 16-key tiles, 4 chained k-MFMAs each ----
        f32x4 S[2];
        #pragma unroll
        for (int t = 0; t < 2; ++t) {
            f32x4 acc = (f32x4)0.0f;
            #pragma unroll
            for (int ks = 0; ks < 4; ++ks)
                acc = __builtin_amdgcn_mfma_f32_16x16x32_bf16(qf[ks], kf[t * 4 + ks], acc, 0, 0, 0);
            S[t] = acc;
        }
        // ---- scale, mask, online softmax (rows live in 16-lane groups) ----
        const int j0 = kc + lm, j1 = kc + 16 + lm;
        #pragma unroll
        for (int r = 0; r < 4; ++r) {
            const int i = q0 + q * 4 + r;
            float v0 = S[0][r] * f;
            float v1 = S[1][r] * f;
            if (j0 > i || j0 < i - WINn) v0 = -1e30f;
            if (j1 > i || j1 < i - WINn) v1 = -1e30f;
            float mx = fmaxf(v0, v1);
            #pragma unroll
            for (int off = 8; off > 0; off >>= 1)
                mx = fmaxf(mx, __shfl_xor(mx, off));
            const float mn = fmaxf(m[r], mx);
            const float alpha = __expf(m[r] - mn);
            m[r] = mn;
            const ushort h0 = f2bf(__expf(v0 - mn));
            const ushort h1 = f2bf(__expf(v1 - mn));
            plds[(q * 4 + r) * 40 + lm]      = h0;
            plds[(q * 4 + r) * 40 + 16 + lm] = h1;
            float ps = bf2f(h0) + bf2f(h1);    // bf16-rounded p's (consistency)
            #pragma unroll
            for (int off = 8; off > 0; off >>= 1)
                ps += __shfl_xor(ps, off);
            lsum[r] = lsum[r] * alpha + ps;
            #pragma unroll
            for (int nt = 0; nt < 8; ++nt) O[nt][r] *= alpha;
        }
        // ---- P (C/D layout) -> A-frag via per-wave LDS round trip ----
        const s16x8 pf = *reinterpret_cast<const s16x8*>(&plds[lm * 40 + q * 8]);
        // ---- P·V: 8 n-tiles of 16 dims ----
        #pragma unroll
        for (int nt = 0; nt < 8; ++nt)
            O[nt] = __builtin_amdgcn_mfma_f32_16x16x32_bf16(pf, vf[nt], O[nt], 0, 0, 0);
    }
    // ---- epilogue: O /= l, write rows q0+q*4+r ----
    #pragma unroll
    for (int r = 0; r < 4; ++r) {
        const float inv = 1.0f / lsum[r];
        const size_t orow = ((size_t)(b * SEQn + q0 + q * 4 + r)) * DMn + h * HDn;
        #pragma unroll
        for (int nt = 0; nt < 8; ++nt)
            AO[orow + nt * 16 + lm] = f2bf(O[nt][r] * inv);
    }
}

extern "C" void kernel_launch(void* const* d_in, const int* in_sizes, int n_in,
                              void* d_out, int out_size, void* d_ws, size_t ws_size,
                              hipStream_t stream)
{
    (void)in_sizes; (void)n_in; (void)out_size; (void)ws_size;
    const float* x  = (const float*)d_in[0];
    const float* WQ = (const float*)d_in[1];
    const float* bQ = (const float*)d_in[2];
    const float* WK = (const float*)d_in[3];
    const float* bK = (const float*)d_in[4];
    const float* WV = (const float*)d_in[5];
    const float* bV = (const float*)d_in[6];
    const float* WO = (const float*)d_in[7];
    const float* bO = (const float*)d_in[8];
    const float* kw = (const float*)d_in[9];
    float* out = (float*)d_out;

    // Workspace — peak 72 MB: xb/Qb/Kb/Vt bf16 16 MB each + one 8 MB WT slot.
    char* ws = (char*)d_ws;
    const size_t AELEMS = (size_t)MROWS * DMn;         // 4096*2048
    ushort* xb = (ushort*)ws;                          // bf16 copy of x
    ushort* Qb = (ushort*)(ws + AELEMS * 2);           // also AO (in-place)
    ushort* Kb = (ushort*)(ws + AELEMS * 4);
    ushort* Vt = (ushort*)(ws + AELEMS * 6);           // [b][h][d][s]
    ushort* WT = (ushort*)(ws + AELEMS * 8);           // reused for all 4 weights

    const dim3 tgrid(64, 64);
    const dim3 tblk(32, 8);
    const dim3 ggrid(DMn / 128, MROWS / 128);          // 16 x 32

    cvt_kernel<<<(int)(AELEMS / 1024), 256, 0, stream>>>(x, xb);

    transpose_cvt_kernel<<<tgrid, tblk, 0, stream>>>(WQ, WT);
    gemm_bt_kernel<0><<<ggrid, 256, 0, stream>>>(xb, WT, bQ, Qb, MROWS, DMn, HIDn);

    transpose_cvt_kernel<<<tgrid, tblk, 0, stream>>>(WK, WT);
    gemm_bt_kernel<0><<<ggrid, 256, 0, stream>>>(xb, WT, bK, Kb, MROWS, DMn, HIDn);

    transpose_cvt_kernel<<<tgrid, tblk, 0, stream>>>(WV, WT);
    gemm_bt_kernel<2><<<ggrid, 256, 0, stream>>>(xb, WT, bV, Vt, MROWS, DMn, HIDn);

    rope_kernel<<<dim3((BATCHn * SEQn * NHn * 64) / 256, 1, 2), 256, 0, stream>>>(Qb, Kb);

    attn_mfma_kernel<<<dim3(BATCHn * NHn * (SEQn / 16)), 64, 0, stream>>>(Qb, Kb, Vt, kw, Qb);

    transpose_cvt_kernel<<<tgrid, tblk, 0, stream>>>(WO, WT);
    gemm_bt_kernel<1><<<ggrid, 256, 0, stream>>>(Qb, WT, bO, out, MROWS, HIDn, DMn);
}

// Round 6
// 496.140 us; speedup vs baseline: 1.0401x; 1.0401x over previous
//
#include <hip/hip_runtime.h>
#include <cstdint>

#define SEQn   2048
#define NHn    16
#define HDn    128
#define DMn    2048   // NH*HD
#define HIDn   2048
#define BATCHn 2
#define WINn   256
#define MROWS  (BATCHn*SEQn)  // 4096
#define WELEMS ((size_t)HIDn * DMn)

typedef short s16x8 __attribute__((ext_vector_type(8)));  // 8 bf16 (4 VGPRs)
typedef float f32x4 __attribute__((ext_vector_type(4)));  // MFMA accumulator

__device__ __forceinline__ float bf2f(ushort x) {
    union { uint u; float f; } v; v.u = ((uint)x) << 16; return v.f;
}
__device__ __forceinline__ ushort f2bf(float f) {
    union { float f; uint u; } v; v.f = f;
    uint u = v.u;
    return (ushort)((u + 0x7FFFu + ((u >> 16) & 1u)) >> 16);  // RNE
}

// --- batched transpose+convert: {WQ,WK,WV}[k][n] fp32 -> WT[z][n][k] bf16 ----
__global__ __launch_bounds__(256)
void transpose_qkv_kernel(const float* __restrict__ WQ, const float* __restrict__ WK,
                          const float* __restrict__ WV, ushort* __restrict__ WT)
{
    __shared__ ushort t[32][33];
    const float* src = (blockIdx.z == 0) ? WQ : (blockIdx.z == 1) ? WK : WV;
    ushort* dst = WT + (size_t)blockIdx.z * WELEMS;
    const int tx = threadIdx.x, ty = threadIdx.y;
    const int n  = blockIdx.x * 32 + tx;
    const int k0 = blockIdx.y * 32;
    #pragma unroll
    for (int r = ty; r < 32; r += 8)
        t[r][tx] = f2bf(src[(size_t)(k0 + r) * 2048 + n]);
    __syncthreads();
    const int k  = k0 + tx;
    const int nb = blockIdx.x * 32;
    #pragma unroll
    for (int r = ty; r < 32; r += 8)
        dst[(size_t)(nb + r) * 2048 + k] = t[tx][r];
}

// ------- single transpose+convert: W[k][n] fp32 -> WT[n][k] bf16 -------------
__global__ __launch_bounds__(256)
void transpose_cvt_kernel(const float* __restrict__ src, ushort* __restrict__ dst)
{
    __shared__ ushort t[32][33];
    const int tx = threadIdx.x, ty = threadIdx.y;
    const int n  = blockIdx.x * 32 + tx;
    const int k0 = blockIdx.y * 32;
    #pragma unroll
    for (int r = ty; r < 32; r += 8)
        t[r][tx] = f2bf(src[(size_t)(k0 + r) * 2048 + n]);
    __syncthreads();
    const int k  = k0 + tx;
    const int nb = blockIdx.x * 32;
    #pragma unroll
    for (int r = ty; r < 32; r += 8)
        dst[(size_t)(nb + r) * 2048 + k] = t[tx][r];
}

// -------- fused QKV GEMM: [Q|K|V](4096x6144) = x(4096x2048) * WT^T + bias ---
// A fp32 (converted to bf16 during LDS staging). Per-block routing is
// wave-uniform: sel = n0g>>11 picks {Q,K,V} weight slab / bias / output.
// 128x128 tile, BK=64, 4 waves (2x2), wave tile 64x64 = 4x4 MFMA 16x16x32.
// C/D: col=lane&15, row=(lane>>4)*4+reg  (m89-verified mapping).
__global__ __launch_bounds__(256)
void gemm_qkv_kernel(const float* __restrict__ A, const ushort* __restrict__ WT,
                     const float* __restrict__ bQ, const float* __restrict__ bK,
                     const float* __restrict__ bV,
                     ushort* __restrict__ Qb, ushort* __restrict__ Kb,
                     ushort* __restrict__ Vt)
{
    __shared__ __align__(16) ushort As[128 * 72];
    __shared__ __align__(16) ushort Bs[128 * 72];
    const int tid = threadIdx.x;
    const int m0  = blockIdx.y * 128;
    const int n0g = blockIdx.x * 128;          // 0..6143
    const int sel = n0g >> 11;                 // 0=Q 1=K 2=V
    const int n0  = n0g & 2047;
    const ushort* BT  = WT + (size_t)sel * WELEMS;
    const float* bias = (sel == 0) ? bQ : (sel == 1) ? bK : bV;
    const int w  = tid >> 6;
    const int l  = tid & 63;
    const int wy = w >> 1, wx = w & 1;
    const int q  = l >> 4, lm = l & 15;

    f32x4 acc[4][4];
    #pragma unroll
    for (int i = 0; i < 4; ++i)
        #pragma unroll
        for (int j = 0; j < 4; ++j) acc[i][j] = (f32x4)0.0f;

    for (int kt = 0; kt < HIDn; kt += 64) {
        #pragma unroll
        for (int it = 0; it < 4; ++it) {
            const int v = tid + it * 256;
            const int r = v >> 3;
            const int c = (v & 7) << 3;
            const float* Af = A + (size_t)(m0 + r) * HIDn + kt + c;
            const float4 a0 = *reinterpret_cast<const float4*>(Af);
            const float4 a1 = *reinterpret_cast<const float4*>(Af + 4);
            ushort* d = &As[r * 72 + c];
            d[0] = f2bf(a0.x); d[1] = f2bf(a0.y); d[2] = f2bf(a0.z); d[3] = f2bf(a0.w);
            d[4] = f2bf(a1.x); d[5] = f2bf(a1.y); d[6] = f2bf(a1.z); d[7] = f2bf(a1.w);
            const uint4 bv = *reinterpret_cast<const uint4*>(BT + (size_t)(n0 + r) * HIDn + kt + c);
            *reinterpret_cast<uint4*>(&Bs[r * 72 + c]) = bv;
        }
        __syncthreads();
        #pragma unroll
        for (int ks = 0; ks < 2; ++ks) {
            s16x8 af[4], bfv[4];
            #pragma unroll
            for (int im = 0; im < 4; ++im)
                af[im] = *reinterpret_cast<const s16x8*>(&As[(wy * 64 + im * 16 + lm) * 72 + ks * 32 + q * 8]);
            #pragma unroll
            for (int in = 0; in < 4; ++in)
                bfv[in] = *reinterpret_cast<const s16x8*>(&Bs[(wx * 64 + in * 16 + lm) * 72 + ks * 32 + q * 8]);
            #pragma unroll
            for (int im = 0; im < 4; ++im)
                #pragma unroll
                for (int in = 0; in < 4; ++in)
                    acc[im][in] = __builtin_amdgcn_mfma_f32_16x16x32_bf16(af[im], bfv[in], acc[im][in], 0, 0, 0);
        }
        __syncthreads();
    }
    #pragma unroll
    for (int in = 0; in < 4; ++in) {
        const int gcol = n0 + wx * 64 + in * 16 + lm;     // local 0..2047
        const float bv = bias[gcol];
        #pragma unroll
        for (int im = 0; im < 4; ++im) {
            const int grow0 = m0 + wy * 64 + im * 16 + q * 4;
            #pragma unroll
            for (int r = 0; r < 4; ++r) {
                const float val = acc[im][in][r] + bv;
                const int grow = grow0 + r;
                if (sel == 0) {
                    Qb[(size_t)grow * DMn + gcol] = f2bf(val);
                } else if (sel == 1) {
                    Kb[(size_t)grow * DMn + gcol] = f2bf(val);
                } else {
                    // Vt[b][h][d][s]
                    const int bb = grow >> 11, s = grow & (SEQn - 1);
                    const int hh = gcol >> 7,  d = gcol & (HDn - 1);
                    Vt[(((size_t)(bb * NHn + hh)) * HDn + d) * SEQn + s] = f2bf(val);
                }
            }
        }
    }
}

// ---- final GEMM: out(4096x2048 fp32) = AO(bf16) * WT^T + bias (fp32) -------
__global__ __launch_bounds__(256)
void gemm_out_kernel(const ushort* __restrict__ A, const ushort* __restrict__ BT,
                     const float* __restrict__ bias, float* __restrict__ C)
{
    __shared__ __align__(16) ushort As[128 * 72];
    __shared__ __align__(16) ushort Bs[128 * 72];
    const int tid = threadIdx.x;
    const int m0 = blockIdx.y * 128;
    const int n0 = blockIdx.x * 128;
    const int w  = tid >> 6;
    const int l  = tid & 63;
    const int wy = w >> 1, wx = w & 1;
    const int q  = l >> 4, lm = l & 15;

    f32x4 acc[4][4];
    #pragma unroll
    for (int i = 0; i < 4; ++i)
        #pragma unroll
        for (int j = 0; j < 4; ++j) acc[i][j] = (f32x4)0.0f;

    for (int kt = 0; kt < DMn; kt += 64) {
        #pragma unroll
        for (int it = 0; it < 4; ++it) {
            const int v = tid + it * 256;
            const int r = v >> 3;
            const int c = (v & 7) << 3;
            const uint4 av = *reinterpret_cast<const uint4*>(A + (size_t)(m0 + r) * DMn + kt + c);
            *reinterpret_cast<uint4*>(&As[r * 72 + c]) = av;
            const uint4 bv = *reinterpret_cast<const uint4*>(BT + (size_t)(n0 + r) * DMn + kt + c);
            *reinterpret_cast<uint4*>(&Bs[r * 72 + c]) = bv;
        }
        __syncthreads();
        #pragma unroll
        for (int ks = 0; ks < 2; ++ks) {
            s16x8 af[4], bfv[4];
            #pragma unroll
            for (int im = 0; im < 4; ++im)
                af[im] = *reinterpret_cast<const s16x8*>(&As[(wy * 64 + im * 16 + lm) * 72 + ks * 32 + q * 8]);
            #pragma unroll
            for (int in = 0; in < 4; ++in)
                bfv[in] = *reinterpret_cast<const s16x8*>(&Bs[(wx * 64 + in * 16 + lm) * 72 + ks * 32 + q * 8]);
            #pragma unroll
            for (int im = 0; im < 4; ++im)
                #pragma unroll
                for (int in = 0; in < 4; ++in)
                    acc[im][in] = __builtin_amdgcn_mfma_f32_16x16x32_bf16(af[im], bfv[in], acc[im][in], 0, 0, 0);
        }
        __syncthreads();
    }
    #pragma unroll
    for (int in = 0; in < 4; ++in) {
        const int gcol = n0 + wx * 64 + in * 16 + lm;
        const float bv = bias[gcol];
        #pragma unroll
        for (int im = 0; im < 4; ++im) {
            const int grow0 = m0 + wy * 64 + im * 16 + q * 4;
            #pragma unroll
            for (int r = 0; r < 4; ++r)
                C[(size_t)(grow0 + r) * HIDn + gcol] = acc[im][in][r] + bv;
        }
    }
}

// ---------------- RoPE in-place on Q and K (bf16): layout (B,S,NH,128) -------
__global__ __launch_bounds__(256)
void rope_kernel(ushort* Qb, ushort* Kb)
{
    const int idx = blockIdx.x * 256 + threadIdx.x;   // (b,s,h,d2), d2 in [0,64)
    ushort* buf = (blockIdx.z == 0) ? Qb : Kb;
    const int d2 = idx & 63;
    const int s  = (idx >> 10) & (SEQn - 1);
    const size_t base = ((size_t)(idx >> 6)) * 128 + d2;
    const float invf = powf(10000.0f, -(float)d2 * (1.0f / 64.0f));
    const float ang = (float)s * invf;
    const float c = cosf(ang), sn = sinf(ang);
    const float t1 = bf2f(buf[base]);
    const float t2 = bf2f(buf[base + 64]);
    buf[base]      = f2bf(t1 * c - t2 * sn);
    buf[base + 64] = f2bf(t1 * sn + t2 * c);
}

// -------- MFMA flash attention: 4 waves/block, 32 queries per wave ----------
// Q/K bf16 [b][s][h][d] (rope'd); Vt bf16 [b][h][d][s]; AO aliases Q in-place
// (1:1 wave<->rows). Per chunk of 32 keys: K/V frags loaded ONCE, feed the
// MFMAs of BOTH 16-query sub-tiles (2x intensity vs r4). Consecutive waves in
// a block = consecutive q-tiles -> overlapping K/V windows stay L1/L2-hot.
__global__ __launch_bounds__(256)
void attn_mfma_kernel(const ushort* Q, const ushort* __restrict__ K,
                      const ushort* __restrict__ Vt, const float* __restrict__ kw,
                      ushort* AO)
{
    __shared__ ushort plds[4][2][16 * 40];  // stride 40: 2-way bank alias = free
    const int w  = threadIdx.x >> 6;
    const int l  = threadIdx.x & 63;
    const int q  = l >> 4, lm = l & 15;
    const int gw = blockIdx.x * 4 + w;      // b(1) | h(4) | qt(6)
    const int qt = gw & 63;
    const int h  = (gw >> 6) & (NHn - 1);
    const int b  = gw >> 10;
    const int q0 = qt * 32;
    const float f = kw[h] * 0.08838834764831845f;   // kw * HD^-0.5

    s16x8 qf[2][4];
    #pragma unroll
    for (int u = 0; u < 2; ++u) {
        const size_t qbase = ((size_t)(b * SEQn + q0 + u * 16 + lm)) * DMn + h * HDn;
        #pragma unroll
        for (int ks = 0; ks < 4; ++ks)
            qf[u][ks] = *reinterpret_cast<const s16x8*>(Q + qbase + ks * 32 + q * 8);
    }

    f32x4 O[2][8];
    float m[2][4], lsum[2][4];
    #pragma unroll
    for (int u = 0; u < 2; ++u)
        #pragma unroll
        for (int r = 0; r < 4; ++r) { m[u][r] = -1e30f; lsum[u][r] = 0.f; }
    #pragma unroll
    for (int u = 0; u < 2; ++u)
        #pragma unroll
        for (int nt = 0; nt < 8; ++nt) O[u][nt] = (f32x4)0.0f;

    const int lo = q0 - WINn;
    const int c0 = lo > 0 ? (lo & ~31) : 0;
    const int nch = (q0 + 32 - c0 + 31) >> 5;

    const size_t kbh = ((size_t)(b * SEQn)) * DMn + h * HDn;
    const size_t vbh = ((size_t)(b * NHn + h)) * HDn * SEQn;

    for (int c = 0; c < nch; ++c) {
        const int kc = c0 + c * 32;
        // ---- prefetch K and V frags for this chunk (shared by both u) ----
        s16x8 kf[8], vf[8];
        #pragma unroll
        for (int t = 0; t < 2; ++t) {
            const size_t krow = kbh + (size_t)(kc + t * 16 + lm) * DMn;
            #pragma unroll
            for (int ks = 0; ks < 4; ++ks)
                kf[t * 4 + ks] = *reinterpret_cast<const s16x8*>(K + krow + ks * 32 + q * 8);
        }
        #pragma unroll
        for (int nt = 0; nt < 8; ++nt)
            vf[nt] = *reinterpret_cast<const s16x8*>(
                Vt + vbh + (size_t)(nt * 16 + lm) * SEQn + kc + q * 8);
        // ---- QK^T + online softmax for both 16-query sub-tiles ----
        const int j0 = kc + lm, j1 = kc + 16 + lm;
        #pragma unroll
        for (int u = 0; u < 2; ++u) {
            f32x4 S[2];
            #pragma unroll
            for (int t = 0; t < 2; ++t) {
                f32x4 acc = (f32x4)0.0f;
                #pragma unroll
                for (int ks = 0; ks < 4; ++ks)
                    acc = __builtin_amdgcn_mfma_f32_16x16x32_bf16(qf[u][ks], kf[t * 4 + ks], acc, 0, 0, 0);
                S[t] = acc;
            }
            #pragma unroll
            for (int r = 0; r < 4; ++r) {
                const int i = q0 + u * 16 + q * 4 + r;
                float v0 = S[0][r] * f;
                float v1 = S[1][r] * f;
                if (j0 > i || j0 < i - WINn) v0 = -1e30f;
                if (j1 > i || j1 < i - WINn) v1 = -1e30f;
                float mx = fmaxf(v0, v1);
                #pragma unroll
                for (int off = 8; off > 0; off >>= 1)
                    mx = fmaxf(mx, __shfl_xor(mx, off));
                const float mn = fmaxf(m[u][r], mx);
                const float alpha = __expf(m[u][r] - mn);
                m[u][r] = mn;
                const ushort h0 = f2bf(__expf(v0 - mn));
                const ushort h1 = f2bf(__expf(v1 - mn));
                plds[w][u][(q * 4 + r) * 40 + lm]      = h0;
                plds[w][u][(q * 4 + r) * 40 + 16 + lm] = h1;
                float ps = bf2f(h0) + bf2f(h1);
                #pragma unroll
                for (int off = 8; off > 0; off >>= 1)
                    ps += __shfl_xor(ps, off);
                lsum[u][r] = lsum[u][r] * alpha + ps;
                #pragma unroll
                for (int nt = 0; nt < 8; ++nt) O[u][nt][r] *= alpha;
            }
        }
        // ---- P -> A-frag via per-wave LDS round trip; P·V for both u ----
        #pragma unroll
        for (int u = 0; u < 2; ++u) {
            const s16x8 pf = *reinterpret_cast<const s16x8*>(&plds[w][u][lm * 40 + q * 8]);
            #pragma unroll
            for (int nt = 0; nt < 8; ++nt)
                O[u][nt] = __builtin_amdgcn_mfma_f32_16x16x32_bf16(pf, vf[nt], O[u][nt], 0, 0, 0);
        }
    }
    // ---- epilogue ----
    #pragma unroll
    for (int u = 0; u < 2; ++u)
        #pragma unroll
        for (int r = 0; r < 4; ++r) {
            const float inv = 1.0f / lsum[u][r];
            const size_t orow = ((size_t)(b * SEQn + q0 + u * 16 + q * 4 + r)) * DMn + h * HDn;
            #pragma unroll
            for (int nt = 0; nt < 8; ++nt)
                AO[orow + nt * 16 + lm] = f2bf(O[u][nt][r] * inv);
        }
}

extern "C" void kernel_launch(void* const* d_in, const int* in_sizes, int n_in,
                              void* d_out, int out_size, void* d_ws, size_t ws_size,
                              hipStream_t stream)
{
    (void)in_sizes; (void)n_in; (void)out_size; (void)ws_size;
    const float* x  = (const float*)d_in[0];
    const float* WQ = (const float*)d_in[1];
    const float* bQ = (const float*)d_in[2];
    const float* WK = (const float*)d_in[3];
    const float* bK = (const float*)d_in[4];
    const float* WV = (const float*)d_in[5];
    const float* bV = (const float*)d_in[6];
    const float* WO = (const float*)d_in[7];
    const float* bO = (const float*)d_in[8];
    const float* kw = (const float*)d_in[9];
    float* out = (float*)d_out;

    // Workspace — peak 72 MB: Qb/Kb/Vt bf16 16 MB each + 24 MB WT (3 slabs).
    char* ws = (char*)d_ws;
    const size_t AELEMS = (size_t)MROWS * DMn;         // 4096*2048
    ushort* Qb = (ushort*)ws;                          // also AO (in-place)
    ushort* Kb = (ushort*)(ws + AELEMS * 2);
    ushort* Vt = (ushort*)(ws + AELEMS * 4);           // [b][h][d][s]
    ushort* WT = (ushort*)(ws + AELEMS * 6);           // 3 x 2048x2048 bf16

    const dim3 tblk(32, 8);

    transpose_qkv_kernel<<<dim3(64, 64, 3), tblk, 0, stream>>>(WQ, WK, WV, WT);

    gemm_qkv_kernel<<<dim3(3 * DMn / 128, MROWS / 128), 256, 0, stream>>>(
        x, WT, bQ, bK, bV, Qb, Kb, Vt);

    rope_kernel<<<dim3((BATCHn * SEQn * NHn * 64) / 256, 1, 2), 256, 0, stream>>>(Qb, Kb);

    attn_mfma_kernel<<<dim3(BATCHn * NHn * (SEQn / 32) / 4), 256, 0, stream>>>(Qb, Kb, Vt, kw, Qb);

    transpose_cvt_kernel<<<dim3(64, 64), tblk, 0, stream>>>(WO, WT);
    gemm_out_kernel<<<dim3(HIDn / 128, MROWS / 128), 256, 0, stream>>>(Qb, WT, bO, out);
}

// Round 7
// 467.119 us; speedup vs baseline: 1.1047x; 1.0621x over previous
//
#include <hip/hip_runtime.h>
#include <cstdint>

#define SEQn   2048
#define NHn    16
#define HDn    128
#define DMn    2048   // NH*HD
#define HIDn   2048
#define BATCHn 2
#define WINn   256
#define MROWS  (BATCHn*SEQn)  // 4096
#define WELEMS ((size_t)HIDn * DMn)

typedef short s16x8 __attribute__((ext_vector_type(8)));  // 8 bf16 (4 VGPRs)
typedef float f32x4 __attribute__((ext_vector_type(4)));  // MFMA accumulator

__device__ __forceinline__ float bf2f(ushort x) {
    union { uint u; float f; } v; v.u = ((uint)x) << 16; return v.f;
}
__device__ __forceinline__ ushort f2bf(float f) {
    union { float f; uint u; } v; v.f = f;
    uint u = v.u;
    return (ushort)((u + 0x7FFFu + ((u >> 16) & 1u)) >> 16);  // RNE
}

// ---------------- x fp32 -> bf16 convert (coalesced, float4 in / ushort4 out)
__global__ __launch_bounds__(256)
void cvt_kernel(const float* __restrict__ src, ushort* __restrict__ dst)
{
    const int i = (blockIdx.x * 256 + threadIdx.x) * 4;
    const float4 v = *reinterpret_cast<const float4*>(src + i);
    ushort4 o;
    o.x = f2bf(v.x); o.y = f2bf(v.y); o.z = f2bf(v.z); o.w = f2bf(v.w);
    *reinterpret_cast<ushort4*>(dst + i) = o;
}

// --- batched transpose+convert: {WQ,WK,WV}[k][n] fp32 -> WT[z][n][k] bf16 ----
__global__ __launch_bounds__(256)
void transpose_qkv_kernel(const float* __restrict__ WQ, const float* __restrict__ WK,
                          const float* __restrict__ WV, ushort* __restrict__ WT)
{
    __shared__ ushort t[32][33];
    const float* src = (blockIdx.z == 0) ? WQ : (blockIdx.z == 1) ? WK : WV;
    ushort* dst = WT + (size_t)blockIdx.z * WELEMS;
    const int tx = threadIdx.x, ty = threadIdx.y;
    const int n  = blockIdx.x * 32 + tx;
    const int k0 = blockIdx.y * 32;
    #pragma unroll
    for (int r = ty; r < 32; r += 8)
        t[r][tx] = f2bf(src[(size_t)(k0 + r) * 2048 + n]);
    __syncthreads();
    const int k  = k0 + tx;
    const int nb = blockIdx.x * 32;
    #pragma unroll
    for (int r = ty; r < 32; r += 8)
        dst[(size_t)(nb + r) * 2048 + k] = t[tx][r];
}

// ------- single transpose+convert: W[k][n] fp32 -> WT[n][k] bf16 -------------
__global__ __launch_bounds__(256)
void transpose_cvt_kernel(const float* __restrict__ src, ushort* __restrict__ dst)
{
    __shared__ ushort t[32][33];
    const int tx = threadIdx.x, ty = threadIdx.y;
    const int n  = blockIdx.x * 32 + tx;
    const int k0 = blockIdx.y * 32;
    #pragma unroll
    for (int r = ty; r < 32; r += 8)
        t[r][tx] = f2bf(src[(size_t)(k0 + r) * 2048 + n]);
    __syncthreads();
    const int k  = k0 + tx;
    const int nb = blockIdx.x * 32;
    #pragma unroll
    for (int r = ty; r < 32; r += 8)
        dst[(size_t)(nb + r) * 2048 + k] = t[tx][r];
}

// -------- fused QKV GEMM: [Q|K|V](4096x6144) = x(4096x2048) * WT^T + bias ---
// ABF16=1: A already bf16 (pure uint4 copy staging). ABF16=0: A fp32,
// converted during staging (ws-too-small fallback).
// Per-block routing wave-uniform: sel = n0g>>11 picks {Q,K,V}.
// 128x128 tile, BK=64, 4 waves (2x2), wave tile 64x64 = 4x4 MFMA 16x16x32.
// C/D: col=lane&15, row=(lane>>4)*4+reg  (m89-verified mapping).
template<int ABF16>
__global__ __launch_bounds__(256)
void gemm_qkv_kernel(const void* __restrict__ Araw, const ushort* __restrict__ WT,
                     const float* __restrict__ bQ, const float* __restrict__ bK,
                     const float* __restrict__ bV,
                     ushort* __restrict__ Qb, ushort* __restrict__ Kb,
                     ushort* __restrict__ Vt)
{
    __shared__ __align__(16) ushort As[128 * 72];
    __shared__ __align__(16) ushort Bs[128 * 72];
    const int tid = threadIdx.x;
    const int m0  = blockIdx.y * 128;
    const int n0g = blockIdx.x * 128;          // 0..6143
    const int sel = n0g >> 11;                 // 0=Q 1=K 2=V
    const int n0  = n0g & 2047;
    const ushort* BT  = WT + (size_t)sel * WELEMS;
    const float* bias = (sel == 0) ? bQ : (sel == 1) ? bK : bV;
    const int w  = tid >> 6;
    const int l  = tid & 63;
    const int wy = w >> 1, wx = w & 1;
    const int q  = l >> 4, lm = l & 15;

    f32x4 acc[4][4];
    #pragma unroll
    for (int i = 0; i < 4; ++i)
        #pragma unroll
        for (int j = 0; j < 4; ++j) acc[i][j] = (f32x4)0.0f;

    for (int kt = 0; kt < HIDn; kt += 64) {
        #pragma unroll
        for (int it = 0; it < 4; ++it) {
            const int v = tid + it * 256;
            const int r = v >> 3;
            const int c = (v & 7) << 3;
            if (ABF16) {
                const uint4 av = *reinterpret_cast<const uint4*>(
                    (const ushort*)Araw + (size_t)(m0 + r) * HIDn + kt + c);
                *reinterpret_cast<uint4*>(&As[r * 72 + c]) = av;
            } else {
                const float* Af = (const float*)Araw + (size_t)(m0 + r) * HIDn + kt + c;
                const float4 a0 = *reinterpret_cast<const float4*>(Af);
                const float4 a1 = *reinterpret_cast<const float4*>(Af + 4);
                ushort* d = &As[r * 72 + c];
                d[0] = f2bf(a0.x); d[1] = f2bf(a0.y); d[2] = f2bf(a0.z); d[3] = f2bf(a0.w);
                d[4] = f2bf(a1.x); d[5] = f2bf(a1.y); d[6] = f2bf(a1.z); d[7] = f2bf(a1.w);
            }
            const uint4 bv = *reinterpret_cast<const uint4*>(BT + (size_t)(n0 + r) * HIDn + kt + c);
            *reinterpret_cast<uint4*>(&Bs[r * 72 + c]) = bv;
        }
        __syncthreads();
        #pragma unroll
        for (int ks = 0; ks < 2; ++ks) {
            s16x8 af[4], bfv[4];
            #pragma unroll
            for (int im = 0; im < 4; ++im)
                af[im] = *reinterpret_cast<const s16x8*>(&As[(wy * 64 + im * 16 + lm) * 72 + ks * 32 + q * 8]);
            #pragma unroll
            for (int in = 0; in < 4; ++in)
                bfv[in] = *reinterpret_cast<const s16x8*>(&Bs[(wx * 64 + in * 16 + lm) * 72 + ks * 32 + q * 8]);
            #pragma unroll
            for (int im = 0; im < 4; ++im)
                #pragma unroll
                for (int in = 0; in < 4; ++in)
                    acc[im][in] = __builtin_amdgcn_mfma_f32_16x16x32_bf16(af[im], bfv[in], acc[im][in], 0, 0, 0);
        }
        __syncthreads();
    }
    #pragma unroll
    for (int in = 0; in < 4; ++in) {
        const int gcol = n0 + wx * 64 + in * 16 + lm;     // local 0..2047
        const float bv = bias[gcol];
        #pragma unroll
        for (int im = 0; im < 4; ++im) {
            const int grow0 = m0 + wy * 64 + im * 16 + q * 4;
            #pragma unroll
            for (int r = 0; r < 4; ++r) {
                const float val = acc[im][in][r] + bv;
                const int grow = grow0 + r;
                if (sel == 0) {
                    Qb[(size_t)grow * DMn + gcol] = f2bf(val);
                } else if (sel == 1) {
                    Kb[(size_t)grow * DMn + gcol] = f2bf(val);
                } else {
                    // Vt[b][h][d][s]
                    const int bb = grow >> 11, s = grow & (SEQn - 1);
                    const int hh = gcol >> 7,  d = gcol & (HDn - 1);
                    Vt[(((size_t)(bb * NHn + hh)) * HDn + d) * SEQn + s] = f2bf(val);
                }
            }
        }
    }
}

// ---- final GEMM: out(4096x2048 fp32) = AO(bf16) * WT^T + bias (fp32) -------
__global__ __launch_bounds__(256)
void gemm_out_kernel(const ushort* __restrict__ A, const ushort* __restrict__ BT,
                     const float* __restrict__ bias, float* __restrict__ C)
{
    __shared__ __align__(16) ushort As[128 * 72];
    __shared__ __align__(16) ushort Bs[128 * 72];
    const int tid = threadIdx.x;
    const int m0 = blockIdx.y * 128;
    const int n0 = blockIdx.x * 128;
    const int w  = tid >> 6;
    const int l  = tid & 63;
    const int wy = w >> 1, wx = w & 1;
    const int q  = l >> 4, lm = l & 15;

    f32x4 acc[4][4];
    #pragma unroll
    for (int i = 0; i < 4; ++i)
        #pragma unroll
        for (int j = 0; j < 4; ++j) acc[i][j] = (f32x4)0.0f;

    for (int kt = 0; kt < DMn; kt += 64) {
        #pragma unroll
        for (int it = 0; it < 4; ++it) {
            const int v = tid + it * 256;
            const int r = v >> 3;
            const int c = (v & 7) << 3;
            const uint4 av = *reinterpret_cast<const uint4*>(A + (size_t)(m0 + r) * DMn + kt + c);
            *reinterpret_cast<uint4*>(&As[r * 72 + c]) = av;
            const uint4 bv = *reinterpret_cast<const uint4*>(BT + (size_t)(n0 + r) * DMn + kt + c);
            *reinterpret_cast<uint4*>(&Bs[r * 72 + c]) = bv;
        }
        __syncthreads();
        #pragma unroll
        for (int ks = 0; ks < 2; ++ks) {
            s16x8 af[4], bfv[4];
            #pragma unroll
            for (int im = 0; im < 4; ++im)
                af[im] = *reinterpret_cast<const s16x8*>(&As[(wy * 64 + im * 16 + lm) * 72 + ks * 32 + q * 8]);
            #pragma unroll
            for (int in = 0; in < 4; ++in)
                bfv[in] = *reinterpret_cast<const s16x8*>(&Bs[(wx * 64 + in * 16 + lm) * 72 + ks * 32 + q * 8]);
            #pragma unroll
            for (int im = 0; im < 4; ++im)
                #pragma unroll
                for (int in = 0; in < 4; ++in)
                    acc[im][in] = __builtin_amdgcn_mfma_f32_16x16x32_bf16(af[im], bfv[in], acc[im][in], 0, 0, 0);
        }
        __syncthreads();
    }
    #pragma unroll
    for (int in = 0; in < 4; ++in) {
        const int gcol = n0 + wx * 64 + in * 16 + lm;
        const float bv = bias[gcol];
        #pragma unroll
        for (int im = 0; im < 4; ++im) {
            const int grow0 = m0 + wy * 64 + im * 16 + q * 4;
            #pragma unroll
            for (int r = 0; r < 4; ++r)
                C[(size_t)(grow0 + r) * HIDn + gcol] = acc[im][in][r] + bv;
        }
    }
}

// ---------------- RoPE in-place on Q and K (bf16): layout (B,S,NH,128) -------
__global__ __launch_bounds__(256)
void rope_kernel(ushort* Qb, ushort* Kb)
{
    const int idx = blockIdx.x * 256 + threadIdx.x;   // (b,s,h,d2), d2 in [0,64)
    ushort* buf = (blockIdx.z == 0) ? Qb : Kb;
    const int d2 = idx & 63;
    const int s  = (idx >> 10) & (SEQn - 1);
    const size_t base = ((size_t)(idx >> 6)) * 128 + d2;
    const float invf = powf(10000.0f, -(float)d2 * (1.0f / 64.0f));
    const float ang = (float)s * invf;
    const float c = cosf(ang), sn = sinf(ang);
    const float t1 = bf2f(buf[base]);
    const float t2 = bf2f(buf[base + 64]);
    buf[base]      = f2bf(t1 * c - t2 * sn);
    buf[base + 64] = f2bf(t1 * sn + t2 * c);
}

// -------- MFMA flash attention (round-4 version, measured 90 us) ------------
// 4 waves/block, one (b,h,16-query tile) per wave. Q/K bf16 [b][s][h][d];
// Vt bf16 [b][h][d][s]; AO aliases Q in-place (1:1 wave<->rows mapping).
__global__ __launch_bounds__(256)
void attn_mfma_kernel(const ushort* Q, const ushort* __restrict__ K,
                      const ushort* __restrict__ Vt, const float* __restrict__ kw,
                      ushort* AO)
{
    __shared__ ushort plds[4][16 * 40];   // per-wave P tile, stride 40 (2-way = free)
    const int w  = threadIdx.x >> 6;
    const int l  = threadIdx.x & 63;
    const int q  = l >> 4, lm = l & 15;
    const int gw = blockIdx.x * 4 + w;     // b(1) | h(4) | qt(7)
    const int qt = gw & 127;
    const int h  = (gw >> 7) & (NHn - 1);
    const int b  = gw >> 11;
    const int q0 = qt * 16;
    const float f = kw[h] * 0.08838834764831845f;   // kw * HD^-0.5

    s16x8 qf[4];
    const size_t qbase = ((size_t)(b * SEQn + q0 + lm)) * DMn + h * HDn;
    #pragma unroll
    for (int ks = 0; ks < 4; ++ks)
        qf[ks] = *reinterpret_cast<const s16x8*>(Q + qbase + ks * 32 + q * 8);

    f32x4 O[8];
    #pragma unroll
    for (int nt = 0; nt < 8; ++nt) O[nt] = (f32x4)0.0f;
    float m[4]    = {-1e30f, -1e30f, -1e30f, -1e30f};
    float lsum[4] = {0.f, 0.f, 0.f, 0.f};

    const int lo = q0 - WINn;
    const int c0 = lo > 0 ? (lo & ~31) : 0;
    const int nch = (q0 + 16 - c0 + 31) >> 5;

    const size_t kbh = ((size_t)(b * SEQn)) * DMn + h * HDn;
    const size_t vbh = ((size_t)(b * NHn + h)) * HDn * SEQn;

    for (int c = 0; c < nch; ++c) {
        const int kc = c0 + c * 32;
        // ---- QK^T: two 16-key tiles, 4 chained k-MFMAs each ----
        f32x4 S[2];
        #pragma unroll
        for (int t = 0; t < 2; ++t) {
            f32x4 acc = (f32x4)0.0f;
            const size_t krow = kbh + (size_t)(kc + t * 16 + lm) * DMn;
            #pragma unroll
            for (int ks = 0; ks < 4; ++ks) {
                const s16x8 kf = *reinterpret_cast<const s16x8*>(K + krow + ks * 32 + q * 8);
                acc = __builtin_amdgcn_mfma_f32_16x16x32_bf16(qf[ks], kf, acc, 0, 0, 0);
            }
            S[t] = acc;
        }
        // ---- scale, mask, online softmax (rows live in 16-lane groups) ----
        const int j0 = kc + lm, j1 = kc + 16 + lm;
        #pragma unroll
        for (int r = 0; r < 4; ++r) {
            const int i = q0 + q * 4 + r;
            float v0 = S[0][r] * f;
            float v1 = S[1][r] * f;
            if (j0 > i || j0 < i - WINn) v0 = -1e30f;
            if (j1 > i || j1 < i - WINn) v1 = -1e30f;
            float mx = fmaxf(v0, v1);
            #pragma unroll
            for (int off = 8; off > 0; off >>= 1)
                mx = fmaxf(mx, __shfl_xor(mx, off));
            const float mn = fmaxf(m[r], mx);
            const float alpha = __expf(m[r] - mn);
            m[r] = mn;
            const ushort h0 = f2bf(__expf(v0 - mn));
            const ushort h1 = f2bf(__expf(v1 - mn));
            plds[w][(q * 4 + r) * 40 + lm]      = h0;
            plds[w][(q * 4 + r) * 40 + 16 + lm] = h1;
            float ps = bf2f(h0) + bf2f(h1);    // bf16-rounded p's (consistency)
            #pragma unroll
            for (int off = 8; off > 0; off >>= 1)
                ps += __shfl_xor(ps, off);
            lsum[r] = lsum[r] * alpha + ps;
            #pragma unroll
            for (int nt = 0; nt < 8; ++nt) O[nt][r] *= alpha;
        }
        // ---- P (C/D layout) -> A-frag via per-wave LDS round trip ----
        const s16x8 pf = *reinterpret_cast<const s16x8*>(&plds[w][lm * 40 + q * 8]);
        // ---- P·V: 8 n-tiles of 16 dims ----
        #pragma unroll
        for (int nt = 0; nt < 8; ++nt) {
            const s16x8 vf = *reinterpret_cast<const s16x8*>(
                Vt + vbh + (size_t)(nt * 16 + lm) * SEQn + kc + q * 8);
            O[nt] = __builtin_amdgcn_mfma_f32_16x16x32_bf16(pf, vf, O[nt], 0, 0, 0);
        }
    }
    // ---- epilogue: O /= l, write rows q0+q*4+r ----
    #pragma unroll
    for (int r = 0; r < 4; ++r) {
        const float inv = 1.0f / lsum[r];
        const size_t orow = ((size_t)(b * SEQn + q0 + q * 4 + r)) * DMn + h * HDn;
        #pragma unroll
        for (int nt = 0; nt < 8; ++nt)
            AO[orow + nt * 16 + lm] = f2bf(O[nt][r] * inv);
    }
}

extern "C" void kernel_launch(void* const* d_in, const int* in_sizes, int n_in,
                              void* d_out, int out_size, void* d_ws, size_t ws_size,
                              hipStream_t stream)
{
    (void)in_sizes; (void)n_in; (void)out_size;
    const float* x  = (const float*)d_in[0];
    const float* WQ = (const float*)d_in[1];
    const float* bQ = (const float*)d_in[2];
    const float* WK = (const float*)d_in[3];
    const float* bK = (const float*)d_in[4];
    const float* WV = (const float*)d_in[5];
    const float* bV = (const float*)d_in[6];
    const float* WO = (const float*)d_in[7];
    const float* bO = (const float*)d_in[8];
    const float* kw = (const float*)d_in[9];
    float* out = (float*)d_out;

    // Workspace: Qb/Kb/Vt bf16 (16 MB each) + WT 3 slabs (24 MB) = 72 MB;
    // + optional xb (16 MB) = 88 MB when ws_size permits.
    char* ws = (char*)d_ws;
    const size_t AELEMS = (size_t)MROWS * DMn;         // 4096*2048
    ushort* Qb = (ushort*)ws;                          // also AO (in-place)
    ushort* Kb = (ushort*)(ws + AELEMS * 2);
    ushort* Vt = (ushort*)(ws + AELEMS * 4);           // [b][h][d][s]
    ushort* WT = (ushort*)(ws + AELEMS * 6);           // 3 x 2048x2048 bf16
    ushort* xb = (ushort*)(ws + AELEMS * 6 + WELEMS * 6);
    const bool have_xb = ws_size >= (size_t)(AELEMS * 6 + WELEMS * 6) + AELEMS * 2;

    const dim3 tblk(32, 8);

    transpose_qkv_kernel<<<dim3(64, 64, 3), tblk, 0, stream>>>(WQ, WK, WV, WT);

    if (have_xb) {
        cvt_kernel<<<(int)(AELEMS / 1024), 256, 0, stream>>>(x, xb);
        gemm_qkv_kernel<1><<<dim3(3 * DMn / 128, MROWS / 128), 256, 0, stream>>>(
            xb, WT, bQ, bK, bV, Qb, Kb, Vt);
    } else {
        gemm_qkv_kernel<0><<<dim3(3 * DMn / 128, MROWS / 128), 256, 0, stream>>>(
            x, WT, bQ, bK, bV, Qb, Kb, Vt);
    }

    rope_kernel<<<dim3((BATCHn * SEQn * NHn * 64) / 256, 1, 2), 256, 0, stream>>>(Qb, Kb);

    attn_mfma_kernel<<<dim3(BATCHn * NHn * (SEQn / 16) / 4), 256, 0, stream>>>(Qb, Kb, Vt, kw, Qb);

    transpose_cvt_kernel<<<dim3(64, 64), tblk, 0, stream>>>(WO, WT);
    gemm_out_kernel<<<dim3(HIDn / 128, MROWS / 128), 256, 0, stream>>>(Qb, WT, bO, out);
}